// Round 20
// baseline (403.357 us; speedup 1.0000x reference)
//
#include <hip/hip_runtime.h>
#include <math.h>

#define B 128
#define N 512
#define M 512
#define D 128

typedef __attribute__((ext_vector_type(8))) short s16x8;
typedef __attribute__((ext_vector_type(4))) short s16x4;
typedef __attribute__((ext_vector_type(4))) float f32x4;

#define MFMA16(a, b, c) __builtin_amdgcn_mfma_f32_16x16x32_bf16(a, b, c, 0, 0, 0)

__device__ __forceinline__ float fast_tanh(float x) {
    x = fminf(fmaxf(x, -15.f), 15.f);
    float E = __expf(2.f * x);
    return 1.f - 2.f / (E + 1.f);
}

__device__ __forceinline__ unsigned short bf16rne(float x) {
    unsigned u = __float_as_uint(x);
    return (unsigned short)((u + 0x7FFF + ((u >> 16) & 1)) >> 16);
}

__device__ __forceinline__ void fsplit(float x, short& h, short& l) {
    unsigned u = __float_as_uint(x);
    h = (short)(u >> 16);
    float fh = __uint_as_float(u & 0xffff0000u);
    l = (short)(__float_as_uint(x - fh) >> 16);
}

__device__ __forceinline__ void fsplit8(float4 x0, float4 x1, s16x8& h, s16x8& l) {
    short a, b;
    fsplit(x0.x, a, b); h[0] = a; l[0] = b;
    fsplit(x0.y, a, b); h[1] = a; l[1] = b;
    fsplit(x0.z, a, b); h[2] = a; l[2] = b;
    fsplit(x0.w, a, b); h[3] = a; l[3] = b;
    fsplit(x1.x, a, b); h[4] = a; l[4] = b;
    fsplit(x1.y, a, b); h[5] = a; l[5] = b;
    fsplit(x1.z, a, b); h[6] = a; l[6] = b;
    fsplit(x1.w, a, b); h[7] = a; l[7] = b;
}

// EB = exp(-a1ls*cd + ninf) -> single bf16 RNE
__device__ __forceinline__ void ebpack(float4 c0, float4 c1, float4 f0, float4 f1,
                                       float a1ls, s16x8& a) {
    a[0] = (short)bf16rne(__expf(fmaf(-a1ls, c0.x, f0.x)));
    a[1] = (short)bf16rne(__expf(fmaf(-a1ls, c0.y, f0.y)));
    a[2] = (short)bf16rne(__expf(fmaf(-a1ls, c0.z, f0.z)));
    a[3] = (short)bf16rne(__expf(fmaf(-a1ls, c0.w, f0.w)));
    a[4] = (short)bf16rne(__expf(fmaf(-a1ls, c1.x, f1.x)));
    a[5] = (short)bf16rne(__expf(fmaf(-a1ls, c1.y, f1.y)));
    a[6] = (short)bf16rne(__expf(fmaf(-a1ls, c1.z, f1.z)));
    a[7] = (short)bf16rne(__expf(fmaf(-a1ls, c1.w, f1.w)));
}

__global__ void k_prep_w(const float* __restrict__ Wk, const float* __restrict__ Wv,
                         const float* __restrict__ Wq,
                         unsigned short* __restrict__ Wk_hi, unsigned short* __restrict__ Wk_lo,
                         unsigned short* __restrict__ Wv_hi, unsigned short* __restrict__ Wv_lo,
                         unsigned short* __restrict__ Wq_hi, unsigned short* __restrict__ Wq_lo) {
    int i = blockIdx.x * 256 + threadIdx.x;  // 0..49151
    short h, l;
    if (i < 16384) {
        fsplit(Wk[i], h, l); Wk_hi[i] = (unsigned short)h; Wk_lo[i] = (unsigned short)l;
    } else if (i < 32768) {
        int j = i - 16384;
        fsplit(Wv[j], h, l); Wv_hi[j] = (unsigned short)h; Wv_lo[j] = (unsigned short)l;
    } else {
        int j = i - 32768; int e = j >> 7, d = j & 127;
        fsplit(Wq[e * 129 + d], h, l); Wq_hi[j] = (unsigned short)h; Wq_lo[j] = (unsigned short)l;
    }
}

// k = enc@Wk^T, v = enc@Wv^T; store bf16-RNE EK, EK*V as [b][e][m] (m-chunk c at
// c ^ (e&3) within 32-m group). Also emits Eb = bf16(enc) [b][m][e] (e-chunk c at
// c ^ (m&7)).
__global__ __launch_bounds__(256) void k_kv(const float* __restrict__ enc,
        const unsigned short* __restrict__ Wk_hi, const unsigned short* __restrict__ Wk_lo,
        const unsigned short* __restrict__ Wv_hi, const unsigned short* __restrict__ Wv_lo,
        unsigned short* __restrict__ EKb, unsigned short* __restrict__ EKVb,
        unsigned short* __restrict__ Eb) {
    int b = blockIdx.y;
    int wave = threadIdx.x >> 6, lane = threadIdx.x & 63;
    int row = lane & 15, kg = lane >> 4;
    int m0 = blockIdx.x * 64 + wave * 16;
    f32x4 acc[16];
#pragma unroll
    for (int i = 0; i < 16; i++) acc[i] = (f32x4)0.f;
    const float* ap = enc + ((size_t)b * M + m0 + row) * D + kg * 8;
    int menc = m0 + row;
#pragma unroll
    for (int ks = 0; ks < 4; ks++) {
        float4 x0 = *(const float4*)(ap + ks * 32);
        float4 x1 = *(const float4*)(ap + ks * 32 + 4);
        s16x8 ah, al;
        fsplit8(x0, x1, ah, al);
        s16x8 ev;
        ev[0] = (short)bf16rne(x0.x); ev[1] = (short)bf16rne(x0.y);
        ev[2] = (short)bf16rne(x0.z); ev[3] = (short)bf16rne(x0.w);
        ev[4] = (short)bf16rne(x1.x); ev[5] = (short)bf16rne(x1.y);
        ev[6] = (short)bf16rne(x1.z); ev[7] = (short)bf16rne(x1.w);
        int c = ks * 4 + kg;
        *(s16x8*)(Eb + ((size_t)b * M + menc) * D + (size_t)((c ^ (menc & 7)) * 8)) = ev;
        int wb = ks * 32 + kg * 8;
#pragma unroll
        for (int ct = 0; ct < 8; ct++) {
            int e = ct * 16 + row;
            s16x8 bh = *(const s16x8*)(Wk_hi + e * D + wb);
            s16x8 bl = *(const s16x8*)(Wk_lo + e * D + wb);
            acc[ct] = MFMA16(ah, bh, acc[ct]);
            acc[ct] = MFMA16(al, bh, acc[ct]);
            acc[ct] = MFMA16(ah, bl, acc[ct]);
            bh = *(const s16x8*)(Wv_hi + e * D + wb);
            bl = *(const s16x8*)(Wv_lo + e * D + wb);
            acc[8 + ct] = MFMA16(ah, bh, acc[8 + ct]);
            acc[8 + ct] = MFMA16(al, bh, acc[8 + ct]);
            acc[8 + ct] = MFMA16(ah, bl, acc[8 + ct]);
        }
    }
#pragma unroll
    for (int ct = 0; ct < 8; ct++) {
        int e = ct * 16 + row;
        s16x4 kb, vb;
#pragma unroll
        for (int r = 0; r < 4; r++) {
            float ek = __expf(acc[ct][r]);
            float ev = ek * acc[8 + ct][r];
            kb[r] = (short)bf16rne(ek);
            vb[r] = (short)bf16rne(ev);
        }
        int m = m0 + kg * 4;
        int chunk = (m & 31) >> 3;
        int p = chunk ^ (e & 3);
        size_t o = ((size_t)b * D + e) * M + (size_t)(m & ~31) + p * 8 + (m & 7);
        *(s16x4*)(EKb + o) = kb;
        *(s16x4*)(EKVb + o) = vb;
    }
}

// MEGA-FUSED: q + numden + aafm + score + softmax. Direct L2 loads.
// Phase-B main loop ROLLED (unroll 1, two parity copies/trip) to shrink the
// instruction footprint below I$; phase D stays unrolled (acc indexing).
__global__ __launch_bounds__(256, 3) void k_fused(
        const float* __restrict__ encl, const float* __restrict__ loadv,
        const float* __restrict__ Wq,
        const unsigned short* __restrict__ Wq_hi, const unsigned short* __restrict__ Wq_lo,
        const float* __restrict__ cd, const float* __restrict__ ninf,
        const unsigned short* __restrict__ EKVb, const unsigned short* __restrict__ EKb,
        const unsigned short* __restrict__ Eb,
        const float* __restrict__ a1p, const float* __restrict__ a2p,
        const float* __restrict__ lsp, float* __restrict__ out) {
    int o = blockIdx.x;
    int xcd = o & 7, j = o >> 3;       // j 0..255
    int b = ((j >> 4) << 3) + xcd;     // 16 b's per XCD (same-b co-resident)
    int nb = j & 15;
    int n0 = nb * 32;
    int w = threadIdx.x >> 6, lane = threadIdx.x & 63;
    int row = lane & 15, kg = lane >> 4;
    __shared__ __align__(16) char afb[32 * 272];   // aafm bounce, stride 272 B
    __shared__ float redm[32][4], reds[32][4];
    float a1ls = a1p[0] * lsp[0];
    float a2ls = a2p[0] * lsp[0];
    const float invs = 0.08838834764831845f;  // 1/sqrt(128)

    // ===== Phase A: q-pass; sigmoid packed to bf16 pairs =====
    f32x4 sqa[2][2];
#pragma unroll
    for (int s = 0; s < 2; s++)
#pragma unroll
        for (int ct = 0; ct < 2; ct++) sqa[s][ct] = (f32x4)0.f;
#pragma unroll
    for (int s = 0; s < 2; s++) {
        const float* ap = encl + ((size_t)b * N + n0 + s * 16 + row) * D + kg * 8;
#pragma unroll
        for (int ks = 0; ks < 4; ks++) {
            float4 x0 = *(const float4*)(ap + ks * 32);
            float4 x1 = *(const float4*)(ap + ks * 32 + 4);
            s16x8 ah, al;
            fsplit8(x0, x1, ah, al);
            int wqo = ks * 32 + kg * 8;
#pragma unroll
            for (int ct = 0; ct < 2; ct++) {
                int e = w * 32 + ct * 16 + row;
                s16x8 bh = *(const s16x8*)(Wq_hi + e * D + wqo);
                s16x8 bl = *(const s16x8*)(Wq_lo + e * D + wqo);
                sqa[s][ct] = MFMA16(ah, bh, sqa[s][ct]);
                sqa[s][ct] = MFMA16(al, bh, sqa[s][ct]);
                sqa[s][ct] = MFMA16(ah, bl, sqa[s][ct]);
            }
        }
    }
    unsigned sqp[2][2][2];   // [s][ct][rpair]: 2 x bf16 sigmoid
#pragma unroll
    for (int s = 0; s < 2; s++)
#pragma unroll
        for (int ct = 0; ct < 2; ct++) {
            int e = w * 32 + ct * 16 + row;
            float wcol = Wq[e * 129 + 128];
#pragma unroll
            for (int rp = 0; rp < 2; rp++) {
                int n = n0 + s * 16 + kg * 4 + rp * 2;
                float q0 = sqa[s][ct][rp * 2] + loadv[(size_t)b * N + n] * wcol;
                float q1 = sqa[s][ct][rp * 2 + 1] + loadv[(size_t)b * N + n + 1] * wcol;
                unsigned lo = bf16rne(1.f / (1.f + __expf(-q0)));
                unsigned hi = bf16rne(1.f / (1.f + __expf(-q1)));
                sqp[s][ct][rp] = lo | (hi << 16);
            }
        }

    // ===== Phase B: num/den; ROLLED loop (2 parity copies/trip) =====
    f32x4 accN[2][2], accD[2][2];
#pragma unroll
    for (int s = 0; s < 2; s++)
#pragma unroll
        for (int i = 0; i < 2; i++) { accN[s][i] = (f32x4)0.f; accD[s][i] = (f32x4)0.f; }
    const float* cdp0 = cd + ((size_t)b * N + n0 + row) * M + kg * 8;
    const float* nfp0 = ninf + ((size_t)b * N + n0 + row) * M + kg * 8;
    const float* cdp1 = cdp0 + (size_t)16 * M;
    const float* nfp1 = nfp0 + (size_t)16 * M;
    int swo = (kg ^ (row & 3)) << 4;   // bytes
    const char* bVp[2]; const char* bKp[2];
#pragma unroll
    for (int ct = 0; ct < 2; ct++) {
        int e = w * 32 + ct * 16 + row;
        bVp[ct] = (const char*)EKVb + (((size_t)b * D + e) * M) * 2 + swo;
        bKp[ct] = (const char*)EKb  + (((size_t)b * D + e) * M) * 2 + swo;
    }
    float4 Rc[2][2][2], Rf[2][2][2];   // [slot][n-set][half]; tile t -> slot t&1
    s16x8 EA[2][2];                    // [parity][n-set]
    s16x8 BV[2][2], BK[2][2];          // [parity][ct]
#define RAWLOAD(sl, mt)                                                          \
    Rc[sl][0][0] = *(const float4*)(cdp0 + (mt) * 32);                           \
    Rc[sl][0][1] = *(const float4*)(cdp0 + (mt) * 32 + 4);                       \
    Rf[sl][0][0] = *(const float4*)(nfp0 + (mt) * 32);                           \
    Rf[sl][0][1] = *(const float4*)(nfp0 + (mt) * 32 + 4);                       \
    Rc[sl][1][0] = *(const float4*)(cdp1 + (mt) * 32);                           \
    Rc[sl][1][1] = *(const float4*)(cdp1 + (mt) * 32 + 4);                       \
    Rf[sl][1][0] = *(const float4*)(nfp1 + (mt) * 32);                           \
    Rf[sl][1][1] = *(const float4*)(nfp1 + (mt) * 32 + 4);
#define EBCONV(p, sl)                                                            \
    ebpack(Rc[sl][0][0], Rc[sl][0][1], Rf[sl][0][0], Rf[sl][0][1], a1ls, EA[p][0]); \
    ebpack(Rc[sl][1][0], Rc[sl][1][1], Rf[sl][1][0], Rf[sl][1][1], a1ls, EA[p][1]);
#define LOADB(p, mt)                                                             \
    BV[p][0] = *(const s16x8*)(bVp[0] + (mt) * 64);                              \
    BV[p][1] = *(const s16x8*)(bVp[1] + (mt) * 64);                              \
    BK[p][0] = *(const s16x8*)(bKp[0] + (mt) * 64);                              \
    BK[p][1] = *(const s16x8*)(bKp[1] + (mt) * 64);
#define BMFMA(p)                                                                 \
    _Pragma("unroll")                                                            \
    for (int ct = 0; ct < 2; ct++) {                                             \
        accN[0][ct] = MFMA16(EA[p][0], BV[p][ct], accN[0][ct]);                  \
        accN[1][ct] = MFMA16(EA[p][1], BV[p][ct], accN[1][ct]);                  \
        accD[0][ct] = MFMA16(EA[p][0], BK[p][ct], accD[0][ct]);                  \
        accD[1][ct] = MFMA16(EA[p][1], BK[p][ct], accD[1][ct]);                  \
    }

    // prologue: B first, then raws; converts before the loop.
    // Invariant entering tile T (parity p=T&1): EA[p]=tile T, EA[p^1]=tile T+1,
    // B[p]=tile T, B[p^1]=tile T+1, raw slot p = tile T+2.
    LOADB(0, 0) LOADB(1, 1)
    RAWLOAD(0, 0) RAWLOAD(1, 1)
    EBCONV(0, 0)
    RAWLOAD(0, 2)
    EBCONV(1, 1)

#pragma unroll 1
    for (int mt = 0; mt < 16; mt += 2) {
        // tile mt (parity 0)
        BMFMA(0)
        if (mt <= 13) { LOADB(0, mt + 2) }
        if (mt <= 13) { EBCONV(0, 0) }               // EA[0] <- tile mt+2 (slot 0)
        if (mt <= 12) { RAWLOAD(1, mt + 3) }         // slot 1 free after its EBCONV
        // tile mt+1 (parity 1)
        BMFMA(1)
        if (mt + 1 <= 13) { LOADB(1, mt + 3) }
        if (mt + 1 <= 13) { EBCONV(1, 1) }           // EA[1] <- tile mt+3 (slot 1)
        if (mt + 1 <= 12) { RAWLOAD(0, mt + 4) }     // slot 0 free after its EBCONV
    }

    // ===== Phase C: aafm = sq*nan_to_num(num/den) -> bf16 into LDS =====
#pragma unroll
    for (int s = 0; s < 2; s++)
#pragma unroll
        for (int ct = 0; ct < 2; ct++) {
            int e = w * 32 + ct * 16 + row;
#pragma unroll
            for (int r = 0; r < 4; r++) {
                int nl = s * 16 + kg * 4 + r;
                float num = accN[s][ct][r], den = accD[s][ct][r];
                float ww = (den != 0.f) ? num / den : 0.f;
                unsigned us = (r & 1) ? (sqp[s][ct][r >> 1] >> 16)
                                      : (sqp[s][ct][r >> 1] & 0xffffu);
                float sq = __uint_as_float(us << 16);
                *(unsigned short*)(afb + nl * 272 + e * 2) = bf16rne(sq * ww);
            }
        }
    __syncthreads();

    // ===== Phase D: score; A-frags from afb; E before CN in issue order =====
    f32x4 acc[2][8];
#pragma unroll
    for (int s = 0; s < 2; s++)
#pragma unroll
        for (int p = 0; p < 8; p++) acc[s][p] = (f32x4)0.f;
    int dsw = row & 7;
    const char* bE = (const char*)Eb + ((size_t)b * M + w * 128 + row) * 256;
    const float* cdD0 = cd + ((size_t)b * N + n0 + kg * 4) * M + w * 128 + row;
    const float* nfD0 = ninf + ((size_t)b * N + n0 + kg * 4) * M + w * 128 + row;
    const float* cdD1 = cdD0 + (size_t)16 * M;
    const float* nfD1 = nfD0 + (size_t)16 * M;
    s16x8 EF[4];
    float cdv[2][4], nfv[2][4];
#define LOAD_E1(pt)                                                              \
    EF[0] = *(const s16x8*)(bE + (size_t)(pt) * 4096 + ((0 + kg) ^ dsw) * 16);   \
    EF[1] = *(const s16x8*)(bE + (size_t)(pt) * 4096 + ((4 + kg) ^ dsw) * 16);   \
    EF[2] = *(const s16x8*)(bE + (size_t)(pt) * 4096 + ((8 + kg) ^ dsw) * 16);   \
    EF[3] = *(const s16x8*)(bE + (size_t)(pt) * 4096 + ((12 + kg) ^ dsw) * 16);
#define LOAD_CN(pt)                                                              \
    _Pragma("unroll")                                                            \
    for (int r = 0; r < 4; r++) {                                                \
        cdv[0][r] = cdD0[(size_t)r * M + (pt) * 16];                             \
        nfv[0][r] = nfD0[(size_t)r * M + (pt) * 16];                             \
        cdv[1][r] = cdD1[(size_t)r * M + (pt) * 16];                             \
        nfv[1][r] = nfD1[(size_t)r * M + (pt) * 16];                             \
    }

    LOAD_E1(0)
    LOAD_CN(0)

#pragma unroll
    for (int p = 0; p < 8; p++) {
#pragma unroll
        for (int es = 0; es < 4; es++) {
            s16x8 a0 = *(const s16x8*)(afb + (size_t)row * 272 + es * 64 + kg * 16);
            s16x8 a1 = *(const s16x8*)(afb + (size_t)(16 + row) * 272 + es * 64 + kg * 16);
            acc[0][p] = MFMA16(a0, EF[es], acc[0][p]);
            acc[1][p] = MFMA16(a1, EF[es], acc[1][p]);
        }
        if (p <= 6) { LOAD_E1(p + 1) }       // WAR after MFMAs; E before CN
        // bias + tanh + mask
#pragma unroll
        for (int s = 0; s < 2; s++)
#pragma unroll
            for (int r = 0; r < 4; r++) {
                acc[s][p][r] = 10.f * fast_tanh(fmaf(acc[s][p][r], invs, -a2ls * cdv[s][r]))
                             + nfv[s][r];
            }
        if (p <= 6) { LOAD_CN(p + 1) }       // WAR after bias consumed
    }

    // ===== softmax over m =====
    float mx[2][4], sm[2][4];
#pragma unroll
    for (int s = 0; s < 2; s++)
#pragma unroll
        for (int r = 0; r < 4; r++) {
            float m = acc[s][0][r];
#pragma unroll
            for (int p = 1; p < 8; p++) m = fmaxf(m, acc[s][p][r]);
#pragma unroll
            for (int sh = 1; sh < 16; sh <<= 1) m = fmaxf(m, __shfl_xor(m, sh, 64));
            mx[s][r] = m;
        }
    if (row == 0) {
#pragma unroll
        for (int s = 0; s < 2; s++)
#pragma unroll
            for (int r = 0; r < 4; r++) redm[s * 16 + kg * 4 + r][w] = mx[s][r];
    }
    __syncthreads();
#pragma unroll
    for (int s = 0; s < 2; s++)
#pragma unroll
        for (int r = 0; r < 4; r++) {
            int nl = s * 16 + kg * 4 + r;
            float m = fmaxf(fmaxf(redm[nl][0], redm[nl][1]),
                            fmaxf(redm[nl][2], redm[nl][3]));
            float sum = 0.f;
#pragma unroll
            for (int p = 0; p < 8; p++) {
                float e = __expf(acc[s][p][r] - m);
                acc[s][p][r] = e;
                sum += e;
            }
#pragma unroll
            for (int sh = 1; sh < 16; sh <<= 1) sum += __shfl_xor(sum, sh, 64);
            sm[s][r] = sum;
        }
    if (row == 0) {
#pragma unroll
        for (int s = 0; s < 2; s++)
#pragma unroll
            for (int r = 0; r < 4; r++) reds[s * 16 + kg * 4 + r][w] = sm[s][r];
    }
    __syncthreads();
#pragma unroll
    for (int s = 0; s < 2; s++)
#pragma unroll
        for (int r = 0; r < 4; r++) {
            int nl = s * 16 + kg * 4 + r;
            float inv = 1.f / (reds[nl][0] + reds[nl][1] + reds[nl][2] + reds[nl][3]);
            size_t ro = ((size_t)b * N + n0 + nl) * M + (size_t)w * 128 + row;
#pragma unroll
            for (int p = 0; p < 8; p++) {
                out[ro + p * 16] = acc[s][p][r] * inv;
            }
        }
}

extern "C" void kernel_launch(void* const* d_in, const int* in_sizes, int n_in,
                              void* d_out, int out_size, void* d_ws, size_t ws_size,
                              hipStream_t stream) {
    const float* encl  = (const float*)d_in[0];
    const float* loadv = (const float*)d_in[1];
    const float* cdist = (const float*)d_in[2];
    const float* ls    = (const float*)d_in[3];
    const float* ninf  = (const float*)d_in[4];
    const float* enc   = (const float*)d_in[5];
    const float* Wq    = (const float*)d_in[6];
    const float* Wk    = (const float*)d_in[7];
    const float* Wv    = (const float*)d_in[8];
    const float* a1    = (const float*)d_in[9];
    const float* a2    = (const float*)d_in[10];
    char* ws = (char*)d_ws;
    unsigned short* EKb     = (unsigned short*)(ws);                    // 16.8 MB
    unsigned short* EKVb    = (unsigned short*)(ws + 16777216);         // 16.8 MB
    unsigned short* Eb      = (unsigned short*)(ws + 33554432);         // 16.8 MB
    unsigned short* Wk_hi   = (unsigned short*)(ws + 50331648);
    unsigned short* Wk_lo   = (unsigned short*)(ws + 50331648 + 32768);
    unsigned short* Wv_hi   = (unsigned short*)(ws + 50331648 + 65536);
    unsigned short* Wv_lo   = (unsigned short*)(ws + 50331648 + 98304);
    unsigned short* Wq_hi   = (unsigned short*)(ws + 50331648 + 131072);
    unsigned short* Wq_lo   = (unsigned short*)(ws + 50331648 + 163840);
    float* out = (float*)d_out;

    k_prep_w<<<192, 256, 0, stream>>>(Wk, Wv, Wq, Wk_hi, Wk_lo, Wv_hi, Wv_lo, Wq_hi, Wq_lo);
    k_kv<<<dim3(8, 128), 256, 0, stream>>>(enc, Wk_hi, Wk_lo, Wv_hi, Wv_lo, EKb, EKVb, Eb);
    k_fused<<<2048, 256, 0, stream>>>(encl, loadv, Wq, Wq_hi, Wq_lo,
                                      cdist, ninf, EKVb, EKb, Eb,
                                      a1, a2, ls, out);
}

// Round 21
// 382.626 us; speedup vs baseline: 1.0542x; 1.0542x over previous
//
#include <hip/hip_runtime.h>
#include <math.h>

#define B 128
#define N 512
#define M 512
#define D 128

typedef __attribute__((ext_vector_type(8))) short s16x8;
typedef __attribute__((ext_vector_type(4))) short s16x4;
typedef __attribute__((ext_vector_type(4))) float f32x4;

#define MFMA16(a, b, c) __builtin_amdgcn_mfma_f32_16x16x32_bf16(a, b, c, 0, 0, 0)

__device__ __forceinline__ float fast_tanh(float x) {
    x = fminf(fmaxf(x, -15.f), 15.f);
    float E = __expf(2.f * x);
    return 1.f - 2.f / (E + 1.f);
}

__device__ __forceinline__ unsigned short bf16rne(float x) {
    unsigned u = __float_as_uint(x);
    return (unsigned short)((u + 0x7FFF + ((u >> 16) & 1)) >> 16);
}

__device__ __forceinline__ void fsplit(float x, short& h, short& l) {
    unsigned u = __float_as_uint(x);
    h = (short)(u >> 16);
    float fh = __uint_as_float(u & 0xffff0000u);
    l = (short)(__float_as_uint(x - fh) >> 16);
}

__device__ __forceinline__ void fsplit8(float4 x0, float4 x1, s16x8& h, s16x8& l) {
    short a, b;
    fsplit(x0.x, a, b); h[0] = a; l[0] = b;
    fsplit(x0.y, a, b); h[1] = a; l[1] = b;
    fsplit(x0.z, a, b); h[2] = a; l[2] = b;
    fsplit(x0.w, a, b); h[3] = a; l[3] = b;
    fsplit(x1.x, a, b); h[4] = a; l[4] = b;
    fsplit(x1.y, a, b); h[5] = a; l[5] = b;
    fsplit(x1.z, a, b); h[6] = a; l[6] = b;
    fsplit(x1.w, a, b); h[7] = a; l[7] = b;
}

// EB = exp(-a1ls*cd + ninf) -> single bf16 RNE
__device__ __forceinline__ void ebpack(float4 c0, float4 c1, float4 f0, float4 f1,
                                       float a1ls, s16x8& a) {
    a[0] = (short)bf16rne(__expf(fmaf(-a1ls, c0.x, f0.x)));
    a[1] = (short)bf16rne(__expf(fmaf(-a1ls, c0.y, f0.y)));
    a[2] = (short)bf16rne(__expf(fmaf(-a1ls, c0.z, f0.z)));
    a[3] = (short)bf16rne(__expf(fmaf(-a1ls, c0.w, f0.w)));
    a[4] = (short)bf16rne(__expf(fmaf(-a1ls, c1.x, f1.x)));
    a[5] = (short)bf16rne(__expf(fmaf(-a1ls, c1.y, f1.y)));
    a[6] = (short)bf16rne(__expf(fmaf(-a1ls, c1.z, f1.z)));
    a[7] = (short)bf16rne(__expf(fmaf(-a1ls, c1.w, f1.w)));
}

__global__ void k_prep_w(const float* __restrict__ Wk, const float* __restrict__ Wv,
                         const float* __restrict__ Wq,
                         unsigned short* __restrict__ Wk_hi, unsigned short* __restrict__ Wk_lo,
                         unsigned short* __restrict__ Wv_hi, unsigned short* __restrict__ Wv_lo,
                         unsigned short* __restrict__ Wq_hi, unsigned short* __restrict__ Wq_lo) {
    int i = blockIdx.x * 256 + threadIdx.x;  // 0..49151
    short h, l;
    if (i < 16384) {
        fsplit(Wk[i], h, l); Wk_hi[i] = (unsigned short)h; Wk_lo[i] = (unsigned short)l;
    } else if (i < 32768) {
        int j = i - 16384;
        fsplit(Wv[j], h, l); Wv_hi[j] = (unsigned short)h; Wv_lo[j] = (unsigned short)l;
    } else {
        int j = i - 32768; int e = j >> 7, d = j & 127;
        fsplit(Wq[e * 129 + d], h, l); Wq_hi[j] = (unsigned short)h; Wq_lo[j] = (unsigned short)l;
    }
}

// k = enc@Wk^T, v = enc@Wv^T; store bf16-RNE EK, EK*V as [b][e][m] (m-chunk c at
// c ^ (e&3) within 32-m group). Also emits Eb = bf16(enc) [b][m][e] (e-chunk c at
// c ^ (m&7)).
__global__ __launch_bounds__(256) void k_kv(const float* __restrict__ enc,
        const unsigned short* __restrict__ Wk_hi, const unsigned short* __restrict__ Wk_lo,
        const unsigned short* __restrict__ Wv_hi, const unsigned short* __restrict__ Wv_lo,
        unsigned short* __restrict__ EKb, unsigned short* __restrict__ EKVb,
        unsigned short* __restrict__ Eb) {
    int b = blockIdx.y;
    int wave = threadIdx.x >> 6, lane = threadIdx.x & 63;
    int row = lane & 15, kg = lane >> 4;
    int m0 = blockIdx.x * 64 + wave * 16;
    f32x4 acc[16];
#pragma unroll
    for (int i = 0; i < 16; i++) acc[i] = (f32x4)0.f;
    const float* ap = enc + ((size_t)b * M + m0 + row) * D + kg * 8;
    int menc = m0 + row;
#pragma unroll
    for (int ks = 0; ks < 4; ks++) {
        float4 x0 = *(const float4*)(ap + ks * 32);
        float4 x1 = *(const float4*)(ap + ks * 32 + 4);
        s16x8 ah, al;
        fsplit8(x0, x1, ah, al);
        s16x8 ev;
        ev[0] = (short)bf16rne(x0.x); ev[1] = (short)bf16rne(x0.y);
        ev[2] = (short)bf16rne(x0.z); ev[3] = (short)bf16rne(x0.w);
        ev[4] = (short)bf16rne(x1.x); ev[5] = (short)bf16rne(x1.y);
        ev[6] = (short)bf16rne(x1.z); ev[7] = (short)bf16rne(x1.w);
        int c = ks * 4 + kg;
        *(s16x8*)(Eb + ((size_t)b * M + menc) * D + (size_t)((c ^ (menc & 7)) * 8)) = ev;
        int wb = ks * 32 + kg * 8;
#pragma unroll
        for (int ct = 0; ct < 8; ct++) {
            int e = ct * 16 + row;
            s16x8 bh = *(const s16x8*)(Wk_hi + e * D + wb);
            s16x8 bl = *(const s16x8*)(Wk_lo + e * D + wb);
            acc[ct] = MFMA16(ah, bh, acc[ct]);
            acc[ct] = MFMA16(al, bh, acc[ct]);
            acc[ct] = MFMA16(ah, bl, acc[ct]);
            bh = *(const s16x8*)(Wv_hi + e * D + wb);
            bl = *(const s16x8*)(Wv_lo + e * D + wb);
            acc[8 + ct] = MFMA16(ah, bh, acc[8 + ct]);
            acc[8 + ct] = MFMA16(al, bh, acc[8 + ct]);
            acc[8 + ct] = MFMA16(ah, bl, acc[8 + ct]);
        }
    }
#pragma unroll
    for (int ct = 0; ct < 8; ct++) {
        int e = ct * 16 + row;
        s16x4 kb, vb;
#pragma unroll
        for (int r = 0; r < 4; r++) {
            float ek = __expf(acc[ct][r]);
            float ev = ek * acc[8 + ct][r];
            kb[r] = (short)bf16rne(ek);
            vb[r] = (short)bf16rne(ev);
        }
        int m = m0 + kg * 4;
        int chunk = (m & 31) >> 3;
        int p = chunk ^ (e & 3);
        size_t o = ((size_t)b * D + e) * M + (size_t)(m & ~31) + p * 8 + (m & 7);
        *(s16x4*)(EKb + o) = kb;
        *(s16x4*)(EKVb + o) = vb;
    }
}

// MEGA-FUSED, 16-ROW BLOCKS (grid 4096): halved per-block register state ->
// more resident blocks for latency hiding. Direct L2 loads, r19 ledger.
__global__ __launch_bounds__(256, 3) void k_fused(
        const float* __restrict__ encl, const float* __restrict__ loadv,
        const float* __restrict__ Wq,
        const unsigned short* __restrict__ Wq_hi, const unsigned short* __restrict__ Wq_lo,
        const float* __restrict__ cd, const float* __restrict__ ninf,
        const unsigned short* __restrict__ EKVb, const unsigned short* __restrict__ EKb,
        const unsigned short* __restrict__ Eb,
        const float* __restrict__ a1p, const float* __restrict__ a2p,
        const float* __restrict__ lsp, float* __restrict__ out) {
    int o = blockIdx.x;
    int xcd = o & 7, j = o >> 3;       // j 0..511
    int b = ((j >> 5) << 3) + xcd;     // 16 b's per XCD (same-b co-resident)
    int nb = j & 31;
    int n0 = nb * 16;
    int w = threadIdx.x >> 6, lane = threadIdx.x & 63;
    int row = lane & 15, kg = lane >> 4;
    __shared__ __align__(16) char afb[16 * 272];   // aafm bounce, stride 272 B
    __shared__ float redm[16][4], reds[16][4];
    float a1ls = a1p[0] * lsp[0];
    float a2ls = a2p[0] * lsp[0];
    const float invs = 0.08838834764831845f;  // 1/sqrt(128)

    // ===== Phase A: q-pass (16 rows); sigmoid packed to bf16 pairs =====
    f32x4 sqa[2];
#pragma unroll
    for (int ct = 0; ct < 2; ct++) sqa[ct] = (f32x4)0.f;
    {
        const float* ap = encl + ((size_t)b * N + n0 + row) * D + kg * 8;
#pragma unroll
        for (int ks = 0; ks < 4; ks++) {
            float4 x0 = *(const float4*)(ap + ks * 32);
            float4 x1 = *(const float4*)(ap + ks * 32 + 4);
            s16x8 ah, al;
            fsplit8(x0, x1, ah, al);
            int wqo = ks * 32 + kg * 8;
#pragma unroll
            for (int ct = 0; ct < 2; ct++) {
                int e = w * 32 + ct * 16 + row;
                s16x8 bh = *(const s16x8*)(Wq_hi + e * D + wqo);
                s16x8 bl = *(const s16x8*)(Wq_lo + e * D + wqo);
                sqa[ct] = MFMA16(ah, bh, sqa[ct]);
                sqa[ct] = MFMA16(al, bh, sqa[ct]);
                sqa[ct] = MFMA16(ah, bl, sqa[ct]);
            }
        }
    }
    unsigned sqp[2][2];   // [ct][rpair]: 2 x bf16 sigmoid
#pragma unroll
    for (int ct = 0; ct < 2; ct++) {
        int e = w * 32 + ct * 16 + row;
        float wcol = Wq[e * 129 + 128];
#pragma unroll
        for (int rp = 0; rp < 2; rp++) {
            int n = n0 + kg * 4 + rp * 2;
            float q0 = sqa[ct][rp * 2] + loadv[(size_t)b * N + n] * wcol;
            float q1 = sqa[ct][rp * 2 + 1] + loadv[(size_t)b * N + n + 1] * wcol;
            unsigned lo = bf16rne(1.f / (1.f + __expf(-q0)));
            unsigned hi = bf16rne(1.f / (1.f + __expf(-q1)));
            sqp[ct][rp] = lo | (hi << 16);
        }
    }

    // ===== Phase B: num/den (16 rows); depth-2 raw slots; B before raw =====
    f32x4 accN[2], accD[2];
#pragma unroll
    for (int i = 0; i < 2; i++) { accN[i] = (f32x4)0.f; accD[i] = (f32x4)0.f; }
    const float* cdp0 = cd + ((size_t)b * N + n0 + row) * M + kg * 8;
    const float* nfp0 = ninf + ((size_t)b * N + n0 + row) * M + kg * 8;
    int swo = (kg ^ (row & 3)) << 4;   // bytes
    const char* bVp[2]; const char* bKp[2];
#pragma unroll
    for (int ct = 0; ct < 2; ct++) {
        int e = w * 32 + ct * 16 + row;
        bVp[ct] = (const char*)EKVb + (((size_t)b * D + e) * M) * 2 + swo;
        bKp[ct] = (const char*)EKb  + (((size_t)b * D + e) * M) * 2 + swo;
    }
    float4 Rc[2][2], Rf[2][2];   // [slot][half]; tile t -> slot t&1
    s16x8 EA[2];                 // [parity]
    s16x8 BV[2][2], BK[2][2];    // [parity][ct]
#define RAWLOAD(sl, mt)                                                          \
    Rc[sl][0] = *(const float4*)(cdp0 + (mt) * 32);                              \
    Rc[sl][1] = *(const float4*)(cdp0 + (mt) * 32 + 4);                          \
    Rf[sl][0] = *(const float4*)(nfp0 + (mt) * 32);                              \
    Rf[sl][1] = *(const float4*)(nfp0 + (mt) * 32 + 4);
#define EBCONV(p, sl)                                                            \
    ebpack(Rc[sl][0], Rc[sl][1], Rf[sl][0], Rf[sl][1], a1ls, EA[p]);
#define LOADB(p, mt)                                                             \
    BV[p][0] = *(const s16x8*)(bVp[0] + (mt) * 64);                              \
    BV[p][1] = *(const s16x8*)(bVp[1] + (mt) * 64);                              \
    BK[p][0] = *(const s16x8*)(bKp[0] + (mt) * 64);                              \
    BK[p][1] = *(const s16x8*)(bKp[1] + (mt) * 64);

    // prologue (r19 ledger): B first, then raws; converts before the loop.
    LOADB(0, 0) LOADB(1, 1)
    RAWLOAD(0, 0) RAWLOAD(1, 1)
    EBCONV(0, 0)
    RAWLOAD(0, 2)
    EBCONV(1, 1)

#pragma unroll
    for (int mt = 0; mt < 16; mt++) {
        int p = mt & 1;
#pragma unroll
        for (int ct = 0; ct < 2; ct++) {
            accN[ct] = MFMA16(EA[p], BV[p][ct], accN[ct]);
            accD[ct] = MFMA16(EA[p], BK[p][ct], accD[ct]);
        }
        if (mt <= 13) { LOADB(p, mt + 2) }
        if (mt <= 13) { EBCONV(p, p) }                   // EA[p] <- tile mt+2 (slot p)
        if (mt <= 12) { RAWLOAD((mt + 1) & 1, mt + 3) }  // slot free after its EBCONV
    }

    // ===== Phase C: aafm = sq*nan_to_num(num/den) -> bf16 into LDS =====
#pragma unroll
    for (int ct = 0; ct < 2; ct++) {
        int e = w * 32 + ct * 16 + row;
#pragma unroll
        for (int r = 0; r < 4; r++) {
            int nl = kg * 4 + r;
            float num = accN[ct][r], den = accD[ct][r];
            float ww = (den != 0.f) ? num / den : 0.f;
            unsigned us = (r & 1) ? (sqp[ct][r >> 1] >> 16)
                                  : (sqp[ct][r >> 1] & 0xffffu);
            float sq = __uint_as_float(us << 16);
            *(unsigned short*)(afb + nl * 272 + e * 2) = bf16rne(sq * ww);
        }
    }
    __syncthreads();

    // ===== Phase D: score (16 n x 128 m per wave); A-frags from afb =====
    f32x4 acc[8];
#pragma unroll
    for (int p = 0; p < 8; p++) acc[p] = (f32x4)0.f;
    int dsw = row & 7;
    const char* bE = (const char*)Eb + ((size_t)b * M + w * 128 + row) * 256;
    const float* cdD0 = cd + ((size_t)b * N + n0 + kg * 4) * M + w * 128 + row;
    const float* nfD0 = ninf + ((size_t)b * N + n0 + kg * 4) * M + w * 128 + row;
    s16x8 EF[4];
    float cdv[4], nfv[4];
#define LOAD_E1(pt)                                                              \
    EF[0] = *(const s16x8*)(bE + (size_t)(pt) * 4096 + ((0 + kg) ^ dsw) * 16);   \
    EF[1] = *(const s16x8*)(bE + (size_t)(pt) * 4096 + ((4 + kg) ^ dsw) * 16);   \
    EF[2] = *(const s16x8*)(bE + (size_t)(pt) * 4096 + ((8 + kg) ^ dsw) * 16);   \
    EF[3] = *(const s16x8*)(bE + (size_t)(pt) * 4096 + ((12 + kg) ^ dsw) * 16);
#define LOAD_CN(pt)                                                              \
    _Pragma("unroll")                                                            \
    for (int r = 0; r < 4; r++) {                                                \
        cdv[r] = cdD0[(size_t)r * M + (pt) * 16];                                \
        nfv[r] = nfD0[(size_t)r * M + (pt) * 16];                                \
    }

    LOAD_E1(0)
    LOAD_CN(0)

#pragma unroll
    for (int p = 0; p < 8; p++) {
#pragma unroll
        for (int es = 0; es < 4; es++) {
            s16x8 a0 = *(const s16x8*)(afb + (size_t)row * 272 + es * 64 + kg * 16);
            acc[p] = MFMA16(a0, EF[es], acc[p]);
        }
        if (p <= 6) { LOAD_E1(p + 1) }       // WAR after MFMAs; E before CN
#pragma unroll
        for (int r = 0; r < 4; r++) {
            acc[p][r] = 10.f * fast_tanh(fmaf(acc[p][r], invs, -a2ls * cdv[r]))
                      + nfv[r];
        }
        if (p <= 6) { LOAD_CN(p + 1) }       // WAR after bias consumed
    }

    // ===== softmax over m =====
    float mx[4], sm[4];
#pragma unroll
    for (int r = 0; r < 4; r++) {
        float m = acc[0][r];
#pragma unroll
        for (int p = 1; p < 8; p++) m = fmaxf(m, acc[p][r]);
#pragma unroll
        for (int sh = 1; sh < 16; sh <<= 1) m = fmaxf(m, __shfl_xor(m, sh, 64));
        mx[r] = m;
    }
    if (row == 0) {
#pragma unroll
        for (int r = 0; r < 4; r++) redm[kg * 4 + r][w] = mx[r];
    }
    __syncthreads();
#pragma unroll
    for (int r = 0; r < 4; r++) {
        int nl = kg * 4 + r;
        float m = fmaxf(fmaxf(redm[nl][0], redm[nl][1]),
                        fmaxf(redm[nl][2], redm[nl][3]));
        float sum = 0.f;
#pragma unroll
        for (int p = 0; p < 8; p++) {
            float e = __expf(acc[p][r] - m);
            acc[p][r] = e;
            sum += e;
        }
#pragma unroll
        for (int sh = 1; sh < 16; sh <<= 1) sum += __shfl_xor(sum, sh, 64);
        sm[r] = sum;
    }
    if (row == 0) {
#pragma unroll
        for (int r = 0; r < 4; r++) reds[kg * 4 + r][w] = sm[r];
    }
    __syncthreads();
#pragma unroll
    for (int r = 0; r < 4; r++) {
        int nl = kg * 4 + r;
        float inv = 1.f / (reds[nl][0] + reds[nl][1] + reds[nl][2] + reds[nl][3]);
        size_t ro = ((size_t)b * N + n0 + nl) * M + (size_t)w * 128 + row;
#pragma unroll
        for (int p = 0; p < 8; p++) {
            out[ro + p * 16] = acc[p][r] * inv;
        }
    }
}

extern "C" void kernel_launch(void* const* d_in, const int* in_sizes, int n_in,
                              void* d_out, int out_size, void* d_ws, size_t ws_size,
                              hipStream_t stream) {
    const float* encl  = (const float*)d_in[0];
    const float* loadv = (const float*)d_in[1];
    const float* cdist = (const float*)d_in[2];
    const float* ls    = (const float*)d_in[3];
    const float* ninf  = (const float*)d_in[4];
    const float* enc   = (const float*)d_in[5];
    const float* Wq    = (const float*)d_in[6];
    const float* Wk    = (const float*)d_in[7];
    const float* Wv    = (const float*)d_in[8];
    const float* a1    = (const float*)d_in[9];
    const float* a2    = (const float*)d_in[10];
    char* ws = (char*)d_ws;
    unsigned short* EKb     = (unsigned short*)(ws);                    // 16.8 MB
    unsigned short* EKVb    = (unsigned short*)(ws + 16777216);         // 16.8 MB
    unsigned short* Eb      = (unsigned short*)(ws + 33554432);         // 16.8 MB
    unsigned short* Wk_hi   = (unsigned short*)(ws + 50331648);
    unsigned short* Wk_lo   = (unsigned short*)(ws + 50331648 + 32768);
    unsigned short* Wv_hi   = (unsigned short*)(ws + 50331648 + 65536);
    unsigned short* Wv_lo   = (unsigned short*)(ws + 50331648 + 98304);
    unsigned short* Wq_hi   = (unsigned short*)(ws + 50331648 + 131072);
    unsigned short* Wq_lo   = (unsigned short*)(ws + 50331648 + 163840);
    float* out = (float*)d_out;

    k_prep_w<<<192, 256, 0, stream>>>(Wk, Wv, Wq, Wk_hi, Wk_lo, Wv_hi, Wv_lo, Wq_hi, Wq_lo);
    k_kv<<<dim3(8, 128), 256, 0, stream>>>(enc, Wk_hi, Wk_lo, Wv_hi, Wv_lo, EKb, EKVb, Eb);
    k_fused<<<4096, 256, 0, stream>>>(encl, loadv, Wq, Wq_hi, Wq_lo,
                                      cdist, ninf, EKVb, EKb, Eb,
                                      a1, a2, ls, out);
}

// Round 22
// 325.950 us; speedup vs baseline: 1.2375x; 1.1739x over previous
//
#include <hip/hip_runtime.h>
#include <math.h>

#define B 128
#define N 512
#define M 512
#define D 128

typedef __attribute__((ext_vector_type(8))) short s16x8;
typedef __attribute__((ext_vector_type(4))) short s16x4;
typedef __attribute__((ext_vector_type(4))) float f32x4;

#define MFMA16(a, b, c) __builtin_amdgcn_mfma_f32_16x16x32_bf16(a, b, c, 0, 0, 0)

__device__ __forceinline__ float fast_tanh(float x) {
    x = fminf(fmaxf(x, -15.f), 15.f);
    float E = __expf(2.f * x);
    return 1.f - 2.f / (E + 1.f);
}

__device__ __forceinline__ unsigned short bf16rne(float x) {
    unsigned u = __float_as_uint(x);
    return (unsigned short)((u + 0x7FFF + ((u >> 16) & 1)) >> 16);
}

__device__ __forceinline__ void fsplit(float x, short& h, short& l) {
    unsigned u = __float_as_uint(x);
    h = (short)(u >> 16);
    float fh = __uint_as_float(u & 0xffff0000u);
    l = (short)(__float_as_uint(x - fh) >> 16);
}

__device__ __forceinline__ void fsplit8(float4 x0, float4 x1, s16x8& h, s16x8& l) {
    short a, b;
    fsplit(x0.x, a, b); h[0] = a; l[0] = b;
    fsplit(x0.y, a, b); h[1] = a; l[1] = b;
    fsplit(x0.z, a, b); h[2] = a; l[2] = b;
    fsplit(x0.w, a, b); h[3] = a; l[3] = b;
    fsplit(x1.x, a, b); h[4] = a; l[4] = b;
    fsplit(x1.y, a, b); h[5] = a; l[5] = b;
    fsplit(x1.z, a, b); h[6] = a; l[6] = b;
    fsplit(x1.w, a, b); h[7] = a; l[7] = b;
}

// EB = exp(-a1ls*cd + ninf) -> single bf16 RNE
__device__ __forceinline__ void ebpack(float4 c0, float4 c1, float4 f0, float4 f1,
                                       float a1ls, s16x8& a) {
    a[0] = (short)bf16rne(__expf(fmaf(-a1ls, c0.x, f0.x)));
    a[1] = (short)bf16rne(__expf(fmaf(-a1ls, c0.y, f0.y)));
    a[2] = (short)bf16rne(__expf(fmaf(-a1ls, c0.z, f0.z)));
    a[3] = (short)bf16rne(__expf(fmaf(-a1ls, c0.w, f0.w)));
    a[4] = (short)bf16rne(__expf(fmaf(-a1ls, c1.x, f1.x)));
    a[5] = (short)bf16rne(__expf(fmaf(-a1ls, c1.y, f1.y)));
    a[6] = (short)bf16rne(__expf(fmaf(-a1ls, c1.z, f1.z)));
    a[7] = (short)bf16rne(__expf(fmaf(-a1ls, c1.w, f1.w)));
}

__global__ void k_prep_w(const float* __restrict__ Wk, const float* __restrict__ Wv,
                         const float* __restrict__ Wq,
                         unsigned short* __restrict__ Wk_hi, unsigned short* __restrict__ Wk_lo,
                         unsigned short* __restrict__ Wv_hi, unsigned short* __restrict__ Wv_lo,
                         unsigned short* __restrict__ Wq_hi, unsigned short* __restrict__ Wq_lo) {
    int i = blockIdx.x * 256 + threadIdx.x;  // 0..49151
    short h, l;
    if (i < 16384) {
        fsplit(Wk[i], h, l); Wk_hi[i] = (unsigned short)h; Wk_lo[i] = (unsigned short)l;
    } else if (i < 32768) {
        int j = i - 16384;
        fsplit(Wv[j], h, l); Wv_hi[j] = (unsigned short)h; Wv_lo[j] = (unsigned short)l;
    } else {
        int j = i - 32768; int e = j >> 7, d = j & 127;
        fsplit(Wq[e * 129 + d], h, l); Wq_hi[j] = (unsigned short)h; Wq_lo[j] = (unsigned short)l;
    }
}

// k = enc@Wk^T, v = enc@Wv^T; store bf16-RNE EK, EK*V as [b][e][m] (m-chunk c at
// c ^ (e&3) within 32-m group). Also emits Eb = bf16(enc) [b][m][e] (e-chunk c at
// c ^ (m&7)).
__global__ __launch_bounds__(256) void k_kv(const float* __restrict__ enc,
        const unsigned short* __restrict__ Wk_hi, const unsigned short* __restrict__ Wk_lo,
        const unsigned short* __restrict__ Wv_hi, const unsigned short* __restrict__ Wv_lo,
        unsigned short* __restrict__ EKb, unsigned short* __restrict__ EKVb,
        unsigned short* __restrict__ Eb) {
    int b = blockIdx.y;
    int wave = threadIdx.x >> 6, lane = threadIdx.x & 63;
    int row = lane & 15, kg = lane >> 4;
    int m0 = blockIdx.x * 64 + wave * 16;
    f32x4 acc[16];
#pragma unroll
    for (int i = 0; i < 16; i++) acc[i] = (f32x4)0.f;
    const float* ap = enc + ((size_t)b * M + m0 + row) * D + kg * 8;
    int menc = m0 + row;
#pragma unroll
    for (int ks = 0; ks < 4; ks++) {
        float4 x0 = *(const float4*)(ap + ks * 32);
        float4 x1 = *(const float4*)(ap + ks * 32 + 4);
        s16x8 ah, al;
        fsplit8(x0, x1, ah, al);
        s16x8 ev;
        ev[0] = (short)bf16rne(x0.x); ev[1] = (short)bf16rne(x0.y);
        ev[2] = (short)bf16rne(x0.z); ev[3] = (short)bf16rne(x0.w);
        ev[4] = (short)bf16rne(x1.x); ev[5] = (short)bf16rne(x1.y);
        ev[6] = (short)bf16rne(x1.z); ev[7] = (short)bf16rne(x1.w);
        int c = ks * 4 + kg;
        *(s16x8*)(Eb + ((size_t)b * M + menc) * D + (size_t)((c ^ (menc & 7)) * 8)) = ev;
        int wb = ks * 32 + kg * 8;
#pragma unroll
        for (int ct = 0; ct < 8; ct++) {
            int e = ct * 16 + row;
            s16x8 bh = *(const s16x8*)(Wk_hi + e * D + wb);
            s16x8 bl = *(const s16x8*)(Wk_lo + e * D + wb);
            acc[ct] = MFMA16(ah, bh, acc[ct]);
            acc[ct] = MFMA16(al, bh, acc[ct]);
            acc[ct] = MFMA16(ah, bl, acc[ct]);
            bh = *(const s16x8*)(Wv_hi + e * D + wb);
            bl = *(const s16x8*)(Wv_lo + e * D + wb);
            acc[8 + ct] = MFMA16(ah, bh, acc[8 + ct]);
            acc[8 + ct] = MFMA16(al, bh, acc[8 + ct]);
            acc[8 + ct] = MFMA16(ah, bl, acc[8 + ct]);
        }
    }
#pragma unroll
    for (int ct = 0; ct < 8; ct++) {
        int e = ct * 16 + row;
        s16x4 kb, vb;
#pragma unroll
        for (int r = 0; r < 4; r++) {
            float ek = __expf(acc[ct][r]);
            float ev = ek * acc[8 + ct][r];
            kb[r] = (short)bf16rne(ek);
            vb[r] = (short)bf16rne(ev);
        }
        int m = m0 + kg * 4;
        int chunk = (m & 31) >> 3;
        int p = chunk ^ (e & 3);
        size_t o = ((size_t)b * D + e) * M + (size_t)(m & ~31) + p * 8 + (m & 7);
        *(s16x4*)(EKb + o) = kb;
        *(s16x4*)(EKVb + o) = vb;
    }
}

// MEGA-FUSED: q + numden + aafm + score + softmax. Direct L2 loads.
// Issue-order: B-operands issued BEFORE younger raw loads (in-order vmcnt
// retirement never full-drains). Raw cd/ninf depth-2; tile t raw lives in slot t&1.
__global__ __launch_bounds__(256, 3) void k_fused(
        const float* __restrict__ encl, const float* __restrict__ loadv,
        const float* __restrict__ Wq,
        const unsigned short* __restrict__ Wq_hi, const unsigned short* __restrict__ Wq_lo,
        const float* __restrict__ cd, const float* __restrict__ ninf,
        const unsigned short* __restrict__ EKVb, const unsigned short* __restrict__ EKb,
        const unsigned short* __restrict__ Eb,
        const float* __restrict__ a1p, const float* __restrict__ a2p,
        const float* __restrict__ lsp, float* __restrict__ out) {
    int o = blockIdx.x;
    int xcd = o & 7, j = o >> 3;       // j 0..255
    int b = ((j >> 4) << 3) + xcd;     // 16 b's per XCD (same-b co-resident)
    int nb = j & 15;
    int n0 = nb * 32;
    int w = threadIdx.x >> 6, lane = threadIdx.x & 63;
    int row = lane & 15, kg = lane >> 4;
    __shared__ __align__(16) char afb[32 * 272];   // aafm bounce, stride 272 B
    __shared__ float redm[32][4], reds[32][4];
    float a1ls = a1p[0] * lsp[0];
    float a2ls = a2p[0] * lsp[0];
    const float invs = 0.08838834764831845f;  // 1/sqrt(128)

    // ===== Phase A: q-pass; sigmoid packed to bf16 pairs =====
    f32x4 sqa[2][2];
#pragma unroll
    for (int s = 0; s < 2; s++)
#pragma unroll
        for (int ct = 0; ct < 2; ct++) sqa[s][ct] = (f32x4)0.f;
#pragma unroll
    for (int s = 0; s < 2; s++) {
        const float* ap = encl + ((size_t)b * N + n0 + s * 16 + row) * D + kg * 8;
#pragma unroll
        for (int ks = 0; ks < 4; ks++) {
            float4 x0 = *(const float4*)(ap + ks * 32);
            float4 x1 = *(const float4*)(ap + ks * 32 + 4);
            s16x8 ah, al;
            fsplit8(x0, x1, ah, al);
            int wqo = ks * 32 + kg * 8;
#pragma unroll
            for (int ct = 0; ct < 2; ct++) {
                int e = w * 32 + ct * 16 + row;
                s16x8 bh = *(const s16x8*)(Wq_hi + e * D + wqo);
                s16x8 bl = *(const s16x8*)(Wq_lo + e * D + wqo);
                sqa[s][ct] = MFMA16(ah, bh, sqa[s][ct]);
                sqa[s][ct] = MFMA16(al, bh, sqa[s][ct]);
                sqa[s][ct] = MFMA16(ah, bl, sqa[s][ct]);
            }
        }
    }
    unsigned sqp[2][2][2];   // [s][ct][rpair]: 2 x bf16 sigmoid
#pragma unroll
    for (int s = 0; s < 2; s++)
#pragma unroll
        for (int ct = 0; ct < 2; ct++) {
            int e = w * 32 + ct * 16 + row;
            float wcol = Wq[e * 129 + 128];
#pragma unroll
            for (int rp = 0; rp < 2; rp++) {
                int n = n0 + s * 16 + kg * 4 + rp * 2;
                float q0 = sqa[s][ct][rp * 2] + loadv[(size_t)b * N + n] * wcol;
                float q1 = sqa[s][ct][rp * 2 + 1] + loadv[(size_t)b * N + n + 1] * wcol;
                unsigned lo = bf16rne(1.f / (1.f + __expf(-q0)));
                unsigned hi = bf16rne(1.f / (1.f + __expf(-q1)));
                sqp[s][ct][rp] = lo | (hi << 16);
            }
        }

    // ===== Phase B: num/den; depth-2 raw slots; B issued before raw =====
    f32x4 accN[2][2], accD[2][2];
#pragma unroll
    for (int s = 0; s < 2; s++)
#pragma unroll
        for (int i = 0; i < 2; i++) { accN[s][i] = (f32x4)0.f; accD[s][i] = (f32x4)0.f; }
    const float* cdp0 = cd + ((size_t)b * N + n0 + row) * M + kg * 8;
    const float* nfp0 = ninf + ((size_t)b * N + n0 + row) * M + kg * 8;
    const float* cdp1 = cdp0 + (size_t)16 * M;
    const float* nfp1 = nfp0 + (size_t)16 * M;
    int swo = (kg ^ (row & 3)) << 4;   // bytes
    const char* bVp[2]; const char* bKp[2];
#pragma unroll
    for (int ct = 0; ct < 2; ct++) {
        int e = w * 32 + ct * 16 + row;
        bVp[ct] = (const char*)EKVb + (((size_t)b * D + e) * M) * 2 + swo;
        bKp[ct] = (const char*)EKb  + (((size_t)b * D + e) * M) * 2 + swo;
    }
    float4 Rc[2][2][2], Rf[2][2][2];   // [slot][n-set][half]; tile t -> slot t&1
    s16x8 EA[2][2];                    // [parity][n-set]
    s16x8 BV[2][2], BK[2][2];          // [parity][ct]
#define RAWLOAD(sl, mt)                                                          \
    Rc[sl][0][0] = *(const float4*)(cdp0 + (mt) * 32);                           \
    Rc[sl][0][1] = *(const float4*)(cdp0 + (mt) * 32 + 4);                       \
    Rf[sl][0][0] = *(const float4*)(nfp0 + (mt) * 32);                           \
    Rf[sl][0][1] = *(const float4*)(nfp0 + (mt) * 32 + 4);                       \
    Rc[sl][1][0] = *(const float4*)(cdp1 + (mt) * 32);                           \
    Rc[sl][1][1] = *(const float4*)(cdp1 + (mt) * 32 + 4);                       \
    Rf[sl][1][0] = *(const float4*)(nfp1 + (mt) * 32);                           \
    Rf[sl][1][1] = *(const float4*)(nfp1 + (mt) * 32 + 4);
#define EBCONV(p, sl)                                                            \
    ebpack(Rc[sl][0][0], Rc[sl][0][1], Rf[sl][0][0], Rf[sl][0][1], a1ls, EA[p][0]); \
    ebpack(Rc[sl][1][0], Rc[sl][1][1], Rf[sl][1][0], Rf[sl][1][1], a1ls, EA[p][1]);
#define LOADB(p, mt)                                                             \
    BV[p][0] = *(const s16x8*)(bVp[0] + (mt) * 64);                              \
    BV[p][1] = *(const s16x8*)(bVp[1] + (mt) * 64);                              \
    BK[p][0] = *(const s16x8*)(bKp[0] + (mt) * 64);                              \
    BK[p][1] = *(const s16x8*)(bKp[1] + (mt) * 64);

    // prologue: B first (needed soonest), then raws; converts before the loop.
    // After this: EA[0]=tile0, EA[1]=tile1, slot0=tile2 raw, B[0]=tile0, B[1]=tile1.
    LOADB(0, 0) LOADB(1, 1)
    RAWLOAD(0, 0) RAWLOAD(1, 1)
    EBCONV(0, 0)
    RAWLOAD(0, 2)      // slot0 free after EBCONV(0,0); holds tile 2
    EBCONV(1, 1)       // EA[1] <- tile 1 (slot1)

#pragma unroll
    for (int mt = 0; mt < 16; mt++) {
        int p = mt & 1;
        // MFMA on tile mt: waits B(mt); younger raw(mt+1), B(mt+1), raw(mt+2) in flight
#pragma unroll
        for (int ct = 0; ct < 2; ct++) {
            accN[0][ct] = MFMA16(EA[p][0], BV[p][ct], accN[0][ct]);
            accN[1][ct] = MFMA16(EA[p][1], BV[p][ct], accN[1][ct]);
            accD[0][ct] = MFMA16(EA[p][0], BK[p][ct], accD[0][ct]);
            accD[1][ct] = MFMA16(EA[p][1], BK[p][ct], accD[1][ct]);
        }
        if (mt <= 13) { LOADB(p, mt + 2) }       // B for tile mt+2 (slot p free)
        if (mt <= 13) { EBCONV(p, p) }           // EA[p] <- tile mt+2 (slot (mt+2)&1 = p)
        if (mt <= 12) { RAWLOAD((mt + 1) & 1, mt + 3) }  // slot (mt+3)&1 free after its EBCONV
    }

    // ===== Phase C: aafm = sq*nan_to_num(num/den) -> bf16 into LDS =====
#pragma unroll
    for (int s = 0; s < 2; s++)
#pragma unroll
        for (int ct = 0; ct < 2; ct++) {
            int e = w * 32 + ct * 16 + row;
#pragma unroll
            for (int r = 0; r < 4; r++) {
                int nl = s * 16 + kg * 4 + r;
                float num = accN[s][ct][r], den = accD[s][ct][r];
                float ww = (den != 0.f) ? num / den : 0.f;
                unsigned us = (r & 1) ? (sqp[s][ct][r >> 1] >> 16)
                                      : (sqp[s][ct][r >> 1] & 0xffffu);
                float sq = __uint_as_float(us << 16);
                *(unsigned short*)(afb + nl * 272 + e * 2) = bf16rne(sq * ww);
            }
        }
    __syncthreads();

    // ===== Phase D: score; A-frags from afb; E before CN in issue order =====
    f32x4 acc[2][8];
#pragma unroll
    for (int s = 0; s < 2; s++)
#pragma unroll
        for (int p = 0; p < 8; p++) acc[s][p] = (f32x4)0.f;
    int dsw = row & 7;
    const char* bE = (const char*)Eb + ((size_t)b * M + w * 128 + row) * 256;
    const float* cdD0 = cd + ((size_t)b * N + n0 + kg * 4) * M + w * 128 + row;
    const float* nfD0 = ninf + ((size_t)b * N + n0 + kg * 4) * M + w * 128 + row;
    const float* cdD1 = cdD0 + (size_t)16 * M;
    const float* nfD1 = nfD0 + (size_t)16 * M;
    s16x8 EF[4];
    float cdv[2][4], nfv[2][4];
#define LOAD_E1(pt)                                                              \
    EF[0] = *(const s16x8*)(bE + (size_t)(pt) * 4096 + ((0 + kg) ^ dsw) * 16);   \
    EF[1] = *(const s16x8*)(bE + (size_t)(pt) * 4096 + ((4 + kg) ^ dsw) * 16);   \
    EF[2] = *(const s16x8*)(bE + (size_t)(pt) * 4096 + ((8 + kg) ^ dsw) * 16);   \
    EF[3] = *(const s16x8*)(bE + (size_t)(pt) * 4096 + ((12 + kg) ^ dsw) * 16);
#define LOAD_CN(pt)                                                              \
    _Pragma("unroll")                                                            \
    for (int r = 0; r < 4; r++) {                                                \
        cdv[0][r] = cdD0[(size_t)r * M + (pt) * 16];                             \
        nfv[0][r] = nfD0[(size_t)r * M + (pt) * 16];                             \
        cdv[1][r] = cdD1[(size_t)r * M + (pt) * 16];                             \
        nfv[1][r] = nfD1[(size_t)r * M + (pt) * 16];                             \
    }

    LOAD_E1(0)
    LOAD_CN(0)

#pragma unroll
    for (int p = 0; p < 8; p++) {
#pragma unroll
        for (int es = 0; es < 4; es++) {
            s16x8 a0 = *(const s16x8*)(afb + (size_t)row * 272 + es * 64 + kg * 16);
            s16x8 a1 = *(const s16x8*)(afb + (size_t)(16 + row) * 272 + es * 64 + kg * 16);
            acc[0][p] = MFMA16(a0, EF[es], acc[0][p]);
            acc[1][p] = MFMA16(a1, EF[es], acc[1][p]);
        }
        if (p <= 6) { LOAD_E1(p + 1) }       // WAR after MFMAs; E before CN
        // bias + tanh + mask
#pragma unroll
        for (int s = 0; s < 2; s++)
#pragma unroll
            for (int r = 0; r < 4; r++) {
                acc[s][p][r] = 10.f * fast_tanh(fmaf(acc[s][p][r], invs, -a2ls * cdv[s][r]))
                             + nfv[s][r];
            }
        if (p <= 6) { LOAD_CN(p + 1) }       // WAR after bias consumed
    }

    // ===== softmax over m =====
    float mx[2][4], sm[2][4];
#pragma unroll
    for (int s = 0; s < 2; s++)
#pragma unroll
        for (int r = 0; r < 4; r++) {
            float m = acc[s][0][r];
#pragma unroll
            for (int p = 1; p < 8; p++) m = fmaxf(m, acc[s][p][r]);
#pragma unroll
            for (int sh = 1; sh < 16; sh <<= 1) m = fmaxf(m, __shfl_xor(m, sh, 64));
            mx[s][r] = m;
        }
    if (row == 0) {
#pragma unroll
        for (int s = 0; s < 2; s++)
#pragma unroll
            for (int r = 0; r < 4; r++) redm[s * 16 + kg * 4 + r][w] = mx[s][r];
    }
    __syncthreads();
#pragma unroll
    for (int s = 0; s < 2; s++)
#pragma unroll
        for (int r = 0; r < 4; r++) {
            int nl = s * 16 + kg * 4 + r;
            float m = fmaxf(fmaxf(redm[nl][0], redm[nl][1]),
                            fmaxf(redm[nl][2], redm[nl][3]));
            float sum = 0.f;
#pragma unroll
            for (int p = 0; p < 8; p++) {
                float e = __expf(acc[s][p][r] - m);
                acc[s][p][r] = e;
                sum += e;
            }
#pragma unroll
            for (int sh = 1; sh < 16; sh <<= 1) sum += __shfl_xor(sum, sh, 64);
            sm[s][r] = sum;
        }
    if (row == 0) {
#pragma unroll
        for (int s = 0; s < 2; s++)
#pragma unroll
            for (int r = 0; r < 4; r++) reds[s * 16 + kg * 4 + r][w] = sm[s][r];
    }
    __syncthreads();
#pragma unroll
    for (int s = 0; s < 2; s++)
#pragma unroll
        for (int r = 0; r < 4; r++) {
            int nl = s * 16 + kg * 4 + r;
            float inv = 1.f / (reds[nl][0] + reds[nl][1] + reds[nl][2] + reds[nl][3]);
            size_t ro = ((size_t)b * N + n0 + nl) * M + (size_t)w * 128 + row;
#pragma unroll
            for (int p = 0; p < 8; p++) {
                out[ro + p * 16] = acc[s][p][r] * inv;
            }
        }
}

extern "C" void kernel_launch(void* const* d_in, const int* in_sizes, int n_in,
                              void* d_out, int out_size, void* d_ws, size_t ws_size,
                              hipStream_t stream) {
    const float* encl  = (const float*)d_in[0];
    const float* loadv = (const float*)d_in[1];
    const float* cdist = (const float*)d_in[2];
    const float* ls    = (const float*)d_in[3];
    const float* ninf  = (const float*)d_in[4];
    const float* enc   = (const float*)d_in[5];
    const float* Wq    = (const float*)d_in[6];
    const float* Wk    = (const float*)d_in[7];
    const float* Wv    = (const float*)d_in[8];
    const float* a1    = (const float*)d_in[9];
    const float* a2    = (const float*)d_in[10];
    char* ws = (char*)d_ws;
    unsigned short* EKb     = (unsigned short*)(ws);                    // 16.8 MB
    unsigned short* EKVb    = (unsigned short*)(ws + 16777216);         // 16.8 MB
    unsigned short* Eb      = (unsigned short*)(ws + 33554432);         // 16.8 MB
    unsigned short* Wk_hi   = (unsigned short*)(ws + 50331648);
    unsigned short* Wk_lo   = (unsigned short*)(ws + 50331648 + 32768);
    unsigned short* Wv_hi   = (unsigned short*)(ws + 50331648 + 65536);
    unsigned short* Wv_lo   = (unsigned short*)(ws + 50331648 + 98304);
    unsigned short* Wq_hi   = (unsigned short*)(ws + 50331648 + 131072);
    unsigned short* Wq_lo   = (unsigned short*)(ws + 50331648 + 163840);
    float* out = (float*)d_out;

    k_prep_w<<<192, 256, 0, stream>>>(Wk, Wv, Wq, Wk_hi, Wk_lo, Wv_hi, Wv_lo, Wq_hi, Wq_lo);
    k_kv<<<dim3(8, 128), 256, 0, stream>>>(enc, Wk_hi, Wk_lo, Wv_hi, Wv_lo, EKb, EKVb, Eb);
    k_fused<<<2048, 256, 0, stream>>>(encl, loadv, Wq, Wq_hi, Wq_lo,
                                      cdist, ninf, EKVb, EKb, Eb,
                                      a1, a2, ls, out);
}